// Round 1
// baseline (902.245 us; speedup 1.0000x reference)
//
#include <hip/hip_runtime.h>

// ---------------------------------------------------------------------------
// LightGCN on MI355X: device-built CSR + 3 atomic-free SpMM layers.
// Node layout: x = [user_weight; item_weight], N = NU + NI, d = 64.
// acc (sum of layer embeddings) lives in d_out; final layer fuses * 0.25.
// ---------------------------------------------------------------------------

__device__ __forceinline__ int wave_incl_scan(int v) {
  int lane = threadIdx.x & 63;
#pragma unroll
  for (int off = 1; off < 64; off <<= 1) {
    int t = __shfl_up(v, off, 64);
    if (lane >= off) v += t;
  }
  return v;
}

__global__ void hist_k(const int* __restrict__ col, int E, int* __restrict__ deg) {
  int i = blockIdx.x * blockDim.x + threadIdx.x;
  int stride = gridDim.x * blockDim.x;
  for (; i < E; i += stride) atomicAdd(&deg[col[i]], 1);
}

__global__ void dis_k(const int* __restrict__ deg, float* __restrict__ dis, int N) {
  int i = blockIdx.x * blockDim.x + threadIdx.x;
  if (i < N) {
    int d = deg[i];
    dis[i] = d > 0 ? 1.0f / sqrtf((float)d) : 0.0f;
  }
}

// --- 3-phase exclusive scan of deg[0..N) into offs[0..N], offs[N] = E -------

__global__ void partial_sum_k(const int* __restrict__ deg, int N, int* __restrict__ partials) {
  int base = blockIdx.x * 1024;
  int tid = threadIdx.x;  // 256
  int s = 0;
#pragma unroll
  for (int j = 0; j < 4; ++j) {
    int i = base + j * 256 + tid;
    if (i < N) s += deg[i];
  }
#pragma unroll
  for (int off = 1; off < 64; off <<= 1) s += __shfl_xor(s, off, 64);
  __shared__ int ws_[4];
  int wid = tid >> 6;
  if ((tid & 63) == 0) ws_[wid] = s;
  __syncthreads();
  if (tid == 0) partials[blockIdx.x] = ws_[0] + ws_[1] + ws_[2] + ws_[3];
}

__global__ void scan_partials_k(int* __restrict__ partials, int NB) {
  int tid = threadIdx.x;  // 1024, requires NB <= 1024
  int v = (tid < NB) ? partials[tid] : 0;
  int incl = wave_incl_scan(v);
  __shared__ int wsum[16];
  int wid = tid >> 6, lane = tid & 63;
  if (lane == 63) wsum[wid] = incl;
  __syncthreads();
  if (tid == 0) {
    int run = 0;
#pragma unroll
    for (int j = 0; j < 16; ++j) { int t = wsum[j]; wsum[j] = run; run += t; }
  }
  __syncthreads();
  if (tid < NB) partials[tid] = incl - v + wsum[wid];
}

__global__ void scan_apply_k(const int* __restrict__ deg, const int* __restrict__ partials,
                             int* __restrict__ offs, int N, int E) {
  int i = blockIdx.x * 1024 + threadIdx.x;
  int v = (i < N) ? deg[i] : 0;
  int incl = wave_incl_scan(v);
  __shared__ int wsum[16];
  int wid = threadIdx.x >> 6, lane = threadIdx.x & 63;
  if (lane == 63) wsum[wid] = incl;
  __syncthreads();
  if (threadIdx.x == 0) {
    int run = 0;
#pragma unroll
    for (int j = 0; j < 16; ++j) { int t = wsum[j]; wsum[j] = run; run += t; }
  }
  __syncthreads();
  if (i < N) offs[i] = incl - v + wsum[wid] + partials[blockIdx.x];
  if (i == 0 && blockIdx.x == 0) offs[N] = E;
}

// --- CSR scatter: edges[p] = {src, bits(norm)} grouped by dst ---------------

__global__ void scatter_k(const int* __restrict__ row, const int* __restrict__ col, int E,
                          const int* __restrict__ offs, int* __restrict__ cursor,
                          const float* __restrict__ dis, int2* __restrict__ edges) {
  int i = blockIdx.x * blockDim.x + threadIdx.x;
  int stride = gridDim.x * blockDim.x;
  for (; i < E; i += stride) {
    int c = col[i], r = row[i];
    int p = offs[c] + atomicAdd(&cursor[c], 1);
    float w = dis[r] * dis[c];
    edges[p] = make_int2(r, __float_as_int(w));
  }
}

__global__ void init_k(const float4* __restrict__ uw, const float4* __restrict__ iw,
                       float4* __restrict__ x, float4* __restrict__ out, int nu4, int nt4) {
  int i = blockIdx.x * blockDim.x + threadIdx.x;
  int stride = gridDim.x * blockDim.x;
  for (; i < nt4; i += stride) {
    float4 v = (i < nu4) ? uw[i] : iw[i - nu4];
    x[i] = v;
    out[i] = v;
  }
}

// --- SpMM layer: one wave per node, lane = dim. out_acc += y; final *0.25 ---

template <int FINAL>
__global__ void spmm_k(const int* __restrict__ offs, const int2* __restrict__ edges,
                       const float* __restrict__ xin, float* __restrict__ xout,
                       float* __restrict__ dout, int N) {
  int wid = blockIdx.x * 4 + (threadIdx.x >> 6);
  int lane = threadIdx.x & 63;
  if (wid >= N) return;
  int n = __builtin_amdgcn_readfirstlane(wid);
  int off0 = __builtin_amdgcn_readfirstlane(offs[n]);
  int off1 = __builtin_amdgcn_readfirstlane(offs[n + 1]);
  float acc = 0.0f;
  int e = off0;
  for (; e + 4 <= off1; e += 4) {
    int2 e0 = edges[e + 0];
    int2 e1 = edges[e + 1];
    int2 e2 = edges[e + 2];
    int2 e3 = edges[e + 3];
    float x0 = xin[e0.x * 64 + lane];
    float x1 = xin[e1.x * 64 + lane];
    float x2 = xin[e2.x * 64 + lane];
    float x3 = xin[e3.x * 64 + lane];
    acc += __int_as_float(e0.y) * x0;
    acc += __int_as_float(e1.y) * x1;
    acc += __int_as_float(e2.y) * x2;
    acc += __int_as_float(e3.y) * x3;
  }
  for (; e < off1; ++e) {
    int2 ee = edges[e];
    acc += __int_as_float(ee.y) * xin[ee.x * 64 + lane];
  }
  int o = n * 64 + lane;
  if (FINAL) {
    dout[o] = (dout[o] + acc) * 0.25f;
  } else {
    xout[o] = acc;
    dout[o] += acc;
  }
}

extern "C" void kernel_launch(void* const* d_in, const int* in_sizes, int n_in,
                              void* d_out, int out_size, void* d_ws, size_t ws_size,
                              hipStream_t stream) {
  const int* edge_index = (const int*)d_in[0];
  const float* uw = (const float*)d_in[1];
  const float* iw = (const float*)d_in[2];
  const int E = in_sizes[0] / 2;
  const int NU = in_sizes[1] / 64;
  const int NI = in_sizes[2] / 64;
  const int N = NU + NI;
  const int NB = (N + 1023) / 1024;

  const int* row = edge_index;      // edge_index[0, :]
  const int* col = edge_index + E;  // edge_index[1, :]

  char* w = (char*)d_ws;
  auto carve = [&](size_t bytes) {
    char* p = w;
    w += (bytes + 255) & ~(size_t)255;
    return (void*)p;
  };
  int* deg = (int*)carve((size_t)2 * N * sizeof(int));  // deg + cursor contiguous
  int* cursor = deg + N;
  int* offs = (int*)carve((size_t)(N + 1) * sizeof(int));
  int* partials = (int*)carve((size_t)NB * sizeof(int));
  float* dis = (float*)carve((size_t)N * sizeof(float));
  int2* edges = (int2*)carve((size_t)E * sizeof(int2));
  float* xa = (float*)carve((size_t)N * 64 * sizeof(float));
  float* xb = (float*)carve((size_t)N * 64 * sizeof(float));

  float* out = (float*)d_out;

  hipMemsetAsync(deg, 0, (size_t)2 * N * sizeof(int), stream);
  hist_k<<<2048, 256, 0, stream>>>(col, E, deg);
  dis_k<<<(N + 255) / 256, 256, 0, stream>>>(deg, dis, N);
  partial_sum_k<<<NB, 256, 0, stream>>>(deg, N, partials);
  scan_partials_k<<<1, 1024, 0, stream>>>(partials, NB);
  scan_apply_k<<<NB, 1024, 0, stream>>>(deg, partials, offs, N, E);
  scatter_k<<<2048, 256, 0, stream>>>(row, col, E, offs, cursor, dis, edges);
  init_k<<<2048, 256, 0, stream>>>((const float4*)uw, (const float4*)iw,
                                   (float4*)xa, (float4*)out, NU * 16, N * 16);

  int sb = (N + 3) / 4;  // 4 waves (nodes) per 256-thread block
  spmm_k<0><<<sb, 256, 0, stream>>>(offs, edges, xa, xb, out, N);
  spmm_k<0><<<sb, 256, 0, stream>>>(offs, edges, xb, xa, out, N);
  spmm_k<1><<<sb, 256, 0, stream>>>(offs, edges, xa, xb, out, N);
}